// Round 2
// baseline (795.899 us; speedup 1.0000x reference)
//
#include <hip/hip_runtime.h>

#define N_NODES  50000
#define N_EDGES  800000
#define D_IN     64
#define D_RADIAL 128
#define NTILES   (N_EDGES / 64)   // 12500, exact

// ---- workspace layout (bytes) ----
#define M_OFF    0ull                         // float m[E*64]      = 204,800,000
#define RANK_OFF 204800000ull                 // int rank[E]        =   3,200,000
#define CNT_OFF  208000000ull                 // int counts[N]      =     200,000
#define OFFS_OFF 208200000ull                 // int off[N+1]       =     200,004
#define CUR_OFF  208400004ull                 // int cursor[N]      =     200,000
#define WS_NEED  208600004ull

typedef __bf16 bf16x8 __attribute__((ext_vector_type(8)));
typedef float  f32x4  __attribute__((ext_vector_type(4)));
typedef short  s16x8  __attribute__((ext_vector_type(8)));

__device__ inline unsigned int pack_bf16_pair(float lo, float hi) {
    return __builtin_amdgcn_perm(__float_as_uint(hi), __float_as_uint(lo), 0x07060302u);
}
__device__ inline short f2bf_rne(float f) {
    unsigned int u = __float_as_uint(f);
    u += 0x7FFFu + ((u >> 16) & 1u);
    return (short)(u >> 16);
}

// ---------------- CSR build ----------------
__global__ __launch_bounds__(256) void hist_kernel(const int* __restrict__ dst,
                                                   int* __restrict__ counts) {
    int i = blockIdx.x * 256 + threadIdx.x;
    if (i < N_EDGES) atomicAdd(&counts[dst[i]], 1);
}

__global__ __launch_bounds__(1024) void scan_kernel(const int* __restrict__ counts,
                                                    int* __restrict__ off,
                                                    int* __restrict__ cursor) {
    __shared__ int buf[1024];
    __shared__ int base_s;
    const int tid = threadIdx.x;
    if (tid == 0) base_s = 0;
    __syncthreads();
    for (int start = 0; start < N_NODES; start += 1024) {
        const int i = start + tid;
        const int v = (i < N_NODES) ? counts[i] : 0;
        buf[tid] = v;
        __syncthreads();
        #pragma unroll
        for (int d = 1; d < 1024; d <<= 1) {
            int t = (tid >= d) ? buf[tid - d] : 0;
            __syncthreads();
            buf[tid] += t;
            __syncthreads();
        }
        const int incl = buf[tid];
        const int base = base_s;
        if (i < N_NODES) {
            off[i]    = base + incl - v;
            cursor[i] = base + incl - v;
        }
        __syncthreads();                      // everyone read base_s
        if (tid == 1023) base_s = base + incl;
        __syncthreads();
    }
    if (tid == 0) off[N_NODES] = base_s;      // == N_EDGES
}

__global__ __launch_bounds__(256) void rank_kernel(const int* __restrict__ dst,
                                                   int* __restrict__ cursor,
                                                   int* __restrict__ rank) {
    int i = blockIdx.x * 256 + threadIdx.x;
    if (i < N_EDGES) rank[i] = atomicAdd(&cursor[dst[i]], 1);
}

// ---------------- main: GEMM + gather(x[src]) + CSR-ordered store ----------------
__global__ __launch_bounds__(256) void edge_msg_csr_kernel(
    const float* __restrict__ x,        // [N, 64]
    const float* __restrict__ eb,       // [E, 128]
    const int*   __restrict__ src,      // [E]
    const float* __restrict__ W,        // [64, 128]
    const float* __restrict__ bias_p,   // [64]
    const int*   __restrict__ rank,     // [E]
    float*       __restrict__ m)        // [E, 64] CSR-ordered messages
{
    const int lane = threadIdx.x & 63;
    const int wv   = threadIdx.x >> 6;
    const int l15  = lane & 15;
    const int quad = lane >> 4;

    bf16x8 wfrag[4][4];
    #pragma unroll
    for (int nt = 0; nt < 4; ++nt) {
        const int d = nt * 16 + l15;
        #pragma unroll
        for (int kt = 0; kt < 4; ++kt) {
            const float* p = W + d * D_RADIAL + kt * 32 + quad * 8;
            s16x8 s;
            #pragma unroll
            for (int j = 0; j < 8; ++j) s[j] = f2bf_rne(p[j]);
            wfrag[nt][kt] = __builtin_bit_cast(bf16x8, s);
        }
    }
    float bv[4];
    #pragma unroll
    for (int nt = 0; nt < 4; ++nt) bv[nt] = bias_p[nt * 16 + l15];

    for (int tile = blockIdx.x; tile < NTILES; tile += gridDim.x) {
        const int ebase = tile * 64 + wv * 16;

        f32x4 acc[4];
        #pragma unroll
        for (int nt = 0; nt < 4; ++nt) acc[nt] = (f32x4){0.f, 0.f, 0.f, 0.f};

        #pragma unroll
        for (int kt = 0; kt < 4; ++kt) {
            const float* p = eb + (long)(ebase + l15) * D_RADIAL + kt * 32 + quad * 8;
            f32x4 a0 = *(const f32x4*)(p);
            f32x4 a1 = *(const f32x4*)(p + 4);
            int4 packed;
            packed.x = pack_bf16_pair(a0[0], a0[1]);
            packed.y = pack_bf16_pair(a0[2], a0[3]);
            packed.z = pack_bf16_pair(a1[0], a1[1]);
            packed.w = pack_bf16_pair(a1[2], a1[3]);
            bf16x8 afrag = __builtin_bit_cast(bf16x8, packed);
            #pragma unroll
            for (int nt = 0; nt < 4; ++nt)
                acc[nt] = __builtin_amdgcn_mfma_f32_16x16x32_bf16(
                    afrag, wfrag[nt][kt], acc[nt], 0, 0, 0);
        }

        const int erow = ebase + quad * 4;
        #pragma unroll
        for (int reg = 0; reg < 4; ++reg) {
            const int e  = erow + reg;
            const int sv = src[e];
            const int rk = rank[e];
            const float* xrow = x + (long)sv * D_IN;
            float*       mrow = m + (long)rk * D_IN;
            #pragma unroll
            for (int nt = 0; nt < 4; ++nt) {
                const int d = nt * 16 + l15;
                mrow[d] = (acc[nt][reg] + bv[nt]) * xrow[d];
            }
        }
    }
}

// ---------------- gather: one wave per node, contiguous segment sum ----------------
__global__ __launch_bounds__(256) void gather_kernel(
    const float* __restrict__ m,      // [E, 64] CSR-ordered
    const int*   __restrict__ off,    // [N+1]
    float*       __restrict__ out)    // [N, 64]
{
    const int lane = threadIdx.x & 63;
    const int wv   = threadIdx.x >> 6;
    const int n    = blockIdx.x * 4 + wv;     // 12500 blocks * 4 waves = 50000
    const int beg  = off[n];
    const int end  = off[n + 1];

    float a0 = 0.f, a1 = 0.f, a2 = 0.f, a3 = 0.f;
    int j = beg;
    for (; j + 4 <= end; j += 4) {
        a0 += m[(long)(j + 0) * D_IN + lane];
        a1 += m[(long)(j + 1) * D_IN + lane];
        a2 += m[(long)(j + 2) * D_IN + lane];
        a3 += m[(long)(j + 3) * D_IN + lane];
    }
    for (; j < end; ++j) a0 += m[(long)j * D_IN + lane];
    out[(long)n * D_IN + lane] = (a0 + a1) + (a2 + a3);
}

// ---------------- fallback (round-1 atomic version) if ws too small ----------------
__global__ __launch_bounds__(256) void edge_msg_atomic_kernel(
    const float* __restrict__ x, const float* __restrict__ eb,
    const int* __restrict__ src, const int* __restrict__ dst,
    const float* __restrict__ W, const float* __restrict__ bias_p,
    float* __restrict__ out)
{
    const int lane = threadIdx.x & 63;
    const int wv   = threadIdx.x >> 6;
    const int l15  = lane & 15;
    const int quad = lane >> 4;

    bf16x8 wfrag[4][4];
    #pragma unroll
    for (int nt = 0; nt < 4; ++nt) {
        const int d = nt * 16 + l15;
        #pragma unroll
        for (int kt = 0; kt < 4; ++kt) {
            const float* p = W + d * D_RADIAL + kt * 32 + quad * 8;
            s16x8 s;
            #pragma unroll
            for (int j = 0; j < 8; ++j) s[j] = f2bf_rne(p[j]);
            wfrag[nt][kt] = __builtin_bit_cast(bf16x8, s);
        }
    }
    float bv[4];
    #pragma unroll
    for (int nt = 0; nt < 4; ++nt) bv[nt] = bias_p[nt * 16 + l15];

    for (int tile = blockIdx.x; tile < NTILES; tile += gridDim.x) {
        const int ebase = tile * 64 + wv * 16;
        f32x4 acc[4];
        #pragma unroll
        for (int nt = 0; nt < 4; ++nt) acc[nt] = (f32x4){0.f, 0.f, 0.f, 0.f};
        #pragma unroll
        for (int kt = 0; kt < 4; ++kt) {
            const float* p = eb + (long)(ebase + l15) * D_RADIAL + kt * 32 + quad * 8;
            f32x4 a0 = *(const f32x4*)(p);
            f32x4 a1 = *(const f32x4*)(p + 4);
            int4 packed;
            packed.x = pack_bf16_pair(a0[0], a0[1]);
            packed.y = pack_bf16_pair(a0[2], a0[3]);
            packed.z = pack_bf16_pair(a1[0], a1[1]);
            packed.w = pack_bf16_pair(a1[2], a1[3]);
            bf16x8 afrag = __builtin_bit_cast(bf16x8, packed);
            #pragma unroll
            for (int nt = 0; nt < 4; ++nt)
                acc[nt] = __builtin_amdgcn_mfma_f32_16x16x32_bf16(
                    afrag, wfrag[nt][kt], acc[nt], 0, 0, 0);
        }
        const int erow = ebase + quad * 4;
        #pragma unroll
        for (int reg = 0; reg < 4; ++reg) {
            const int e  = erow + reg;
            const int sv = src[e];
            const int dv = __builtin_nontemporal_load(&dst[e]);
            const float* xrow = x   + (long)sv * D_IN;
            float*       orow = out + (long)dv * D_IN;
            #pragma unroll
            for (int nt = 0; nt < 4; ++nt) {
                const int d = nt * 16 + l15;
                unsafeAtomicAdd(orow + d, (acc[nt][reg] + bv[nt]) * xrow[d]);
            }
        }
    }
}

extern "C" void kernel_launch(void* const* d_in, const int* in_sizes, int n_in,
                              void* d_out, int out_size, void* d_ws, size_t ws_size,
                              hipStream_t stream) {
    const float* x    = (const float*)d_in[0];
    const float* eb   = (const float*)d_in[1];
    const int*   src  = (const int*)d_in[2];
    const int*   dst  = (const int*)d_in[3];
    const float* W    = (const float*)d_in[4];
    const float* bias = (const float*)d_in[5];
    float* out = (float*)d_out;

    if (ws_size < WS_NEED) {
        // fallback: atomic scatter (round-1 path)
        hipMemsetAsync(d_out, 0, (size_t)N_NODES * D_IN * sizeof(float), stream);
        edge_msg_atomic_kernel<<<2500, 256, 0, stream>>>(x, eb, src, dst, W, bias, out);
        return;
    }

    char* ws = (char*)d_ws;
    float* m      = (float*)(ws + M_OFF);
    int*   rank   = (int*)  (ws + RANK_OFF);
    int*   counts = (int*)  (ws + CNT_OFF);
    int*   off    = (int*)  (ws + OFFS_OFF);
    int*   cursor = (int*)  (ws + CUR_OFF);

    hipMemsetAsync(counts, 0, (size_t)N_NODES * sizeof(int), stream);
    hist_kernel<<<(N_EDGES + 255) / 256, 256, 0, stream>>>(dst, counts);
    scan_kernel<<<1, 1024, 0, stream>>>(counts, off, cursor);
    rank_kernel<<<(N_EDGES + 255) / 256, 256, 0, stream>>>(dst, cursor, rank);
    edge_msg_csr_kernel<<<2500, 256, 0, stream>>>(x, eb, src, W, bias, rank, m);
    gather_kernel<<<N_NODES / 4, 256, 0, stream>>>(m, off, out);
}